// Round 17
// baseline (512.613 us; speedup 1.0000x reference)
//
#include <hip/hip_runtime.h>
#include <hip/hip_bf16.h>

using f32x4  = __attribute__((ext_vector_type(4))) float;
using short8 = __attribute__((ext_vector_type(8))) short;
using bf16   = __hip_bfloat16;

constexpr int BATCH = 16;
constexpr int CH    = 256;
constexpr int HH    = 80;
constexpr int WW    = 80;
constexpr int NPIX  = HH * WW;   // 6400

__device__ __forceinline__ float b2f(unsigned short u) {
    union { unsigned int i; float f; } x;
    x.i = ((unsigned int)u) << 16;
    return x.f;
}

// global -> LDS direct copy, 16B per lane.
typedef __attribute__((address_space(3))) void  lds_void;
typedef __attribute__((address_space(1))) const void glb_void;
__device__ __forceinline__ void glds16(const void* g, void* l) {
    __builtin_amdgcn_global_load_lds((glb_void*)(unsigned long long)g,
                                     (lds_void*)(unsigned int)(unsigned long long)l,
                                     16, 0, 0);
}

// ---------------------------------------------------------------------------
// Kernel 0: convert weights fp32 -> bf16.
// ---------------------------------------------------------------------------
__global__ __launch_bounds__(256) void convert_w(
    const float* __restrict__ Wq, const float* __restrict__ Wk,
    const float* __restrict__ Wv, bf16* __restrict__ Wb)
{
    const int elem = blockIdx.x * 256 + threadIdx.x;
    const int mat  = blockIdx.y;
    const float* src = (mat == 0) ? Wq : (mat == 1) ? Wk : Wv;
    Wb[(size_t)mat * CH * CH + elem] = __float2bfloat16(src[elem]);
}

// ---------------------------------------------------------------------------
// Kernel 1: x [b][c][n] fp32 -> x_t [bl][n][c] bf16 (tiled transpose,
// packed ushort4 stores).  At HBM BW floor (157 MB ~ 25 us).
// ---------------------------------------------------------------------------
__global__ __launch_bounds__(256) void transpose_cast(
    const float* __restrict__ x, bf16* __restrict__ xt, int b0)
{
    __shared__ float t[64][65];
    const int b  = b0 + blockIdx.z;
    const int n0 = blockIdx.x * 64;
    const int c0 = blockIdx.y * 64;
    const float* xb = x + (size_t)b * CH * NPIX;
    const int tid = threadIdx.x;

    {
        const int nl  = tid & 63;
        const int cl0 = tid >> 6;
        #pragma unroll
        for (int i = 0; i < 16; ++i) {
            const int cl = cl0 + i * 4;
            t[cl][nl] = xb[(size_t)(c0 + cl) * NPIX + n0 + nl];
        }
    }
    __syncthreads();
    {
        bf16* xtb = xt + (size_t)blockIdx.z * NPIX * CH;
        const int cp  = (tid & 15) * 4;
        const int nl0 = tid >> 4;
        #pragma unroll
        for (int i = 0; i < 4; ++i) {
            const int nl = nl0 + i * 16;
            ushort4 pk;
            #pragma unroll
            for (int j = 0; j < 4; ++j) {
                const bf16 h = __float2bfloat16(t[cp + j][nl]);
                ((unsigned short*)&pk)[j] = *(const unsigned short*)&h;
            }
            *(ushort4*)(xtb + (size_t)(n0 + nl) * CH + c0 + cp) = pk;
        }
    }
}

// ---------------------------------------------------------------------------
// Kernel 2 (r8 best): MFMA GEMM, A-resident + q/k/v fused.
// Empirical best across r8-r15 variants (93.5 us).
// grid (NPIX/128, CH/128, cnb)  block 256 (4 waves, each 64x64)
// ---------------------------------------------------------------------------
__global__ __launch_bounds__(256, 2) void qkv_mfma(
    const bf16* __restrict__ xt, const bf16* __restrict__ Wb,
    const float* __restrict__ bq, const float* __restrict__ bk,
    const float* __restrict__ bv,
    bf16* __restrict__ qt, bf16* __restrict__ kt, bf16* __restrict__ vt)
{
    const int bl = blockIdx.z;
    const int n0 = blockIdx.x * 128;
    const int o0 = blockIdx.y * 128;
    const bf16* A = xt + (size_t)bl * NPIX * CH;

    __shared__ char As[128 * 512];     // 64 KB, full K=256
    __shared__ char Bs[2][128 * 64];   // 16 KB, double-buffered

    const int tid = threadIdx.x;
    const int wv  = tid >> 6, ln = tid & 63;
    const int wr  = wv >> 1,  wc = wv & 1;
    const int lm  = ln & 15,  lk = ln >> 4;

    #pragma unroll
    for (int t = 0; t < 16; ++t) {
        const int idx = t * 256 + tid;           // 0..4095 (16B units)
        const int row = idx >> 5, pos = idx & 31;
        const int chk = pos ^ (row & 7);
        glds16(A + (size_t)(n0 + row) * CH + chk * 8, &As[idx * 16]);
    }

    auto stageB = [&](int buf, const bf16* Wm, int k0) {
        #pragma unroll
        for (int it = 0; it < 2; ++it) {
            const int idx = it * 256 + tid;      // 0..511
            const int row = idx >> 2, pos = idx & 3;
            const int chk = pos ^ ((row >> 1) & 3);
            glds16(Wm + (size_t)(o0 + row) * CH + k0 + chk * 8, &Bs[buf][idx * 16]);
        }
    };

    stageB(0, Wb, 0);
    int buf = 0;

    bf16* const outs[3] = { qt + (size_t)bl * CH * NPIX,
                            kt + (size_t)bl * CH * NPIX,
                            vt + (size_t)bl * CH * NPIX };
    const float* const biases[3] = { bq, bk, bv };

    #pragma unroll
    for (int m = 0; m < 3; ++m) {
        f32x4 acc[4][4];
        #pragma unroll
        for (int i = 0; i < 4; ++i)
            #pragma unroll
            for (int j = 0; j < 4; ++j)
                #pragma unroll
                for (int r = 0; r < 4; ++r) acc[i][j][r] = 0.f;

        #pragma unroll
        for (int t = 0; t < 8; ++t) {
            __syncthreads();
            const int s = m * 8 + t;
            if (s < 23) {
                const int ns = s + 1;
                stageB(buf ^ 1, Wb + (size_t)(ns >> 3) * CH * CH, (ns & 7) * 32);
            }

            short8 afr[4], bfr[4];
            #pragma unroll
            for (int i = 0; i < 4; ++i) {
                const int row = wr * 64 + i * 16 + lm;
                const int chunk = (t * 4 + lk) ^ (row & 7);
                afr[i] = *(const short8*)&As[row * 512 + chunk * 16];
            }
            #pragma unroll
            for (int j = 0; j < 4; ++j) {
                const int row = wc * 64 + j * 16 + lm;
                const int chk = lk ^ ((row >> 1) & 3);
                bfr[j] = *(const short8*)&Bs[buf][row * 64 + chk * 16];
            }
            #pragma unroll
            for (int i = 0; i < 4; ++i)
                #pragma unroll
                for (int j = 0; j < 4; ++j)
                    acc[i][j] = __builtin_amdgcn_mfma_f32_16x16x32_bf16(
                        afr[i], bfr[j], acc[i][j], 0, 0, 0);
            buf ^= 1;
        }

        bf16* out = outs[m];
        const float* bias = biases[m];
        #pragma unroll
        for (int j = 0; j < 4; ++j) {
            const int o = o0 + wc * 64 + j * 16 + lm;
            const float bs = bias[o];
            #pragma unroll
            for (int i = 0; i < 4; ++i) {
                const int nb = n0 + wr * 64 + i * 16 + lk * 4;
                ushort4 pk;
                #pragma unroll
                for (int r = 0; r < 4; ++r) {
                    const bf16 h = __float2bfloat16(acc[i][j][r] + bs);
                    ((unsigned short*)&pk)[r] = *(const unsigned short*)&h;
                }
                *(ushort4*)(out + (size_t)o * NPIX + nb) = pk;
            }
        }
    }
}

// ---------------------------------------------------------------------------
// Kernel 3: scores v6 — wave = 2 quads x 32 c-chunks (8 ch each).
// 2x the waves of v5 (12800 waves = 50/CU), chain halved to 8 c-iters
// (fully unrolled -> all 32 loads in flight).  Butterfly shfl_xor
// (2,4,8,16,32); chunks 0-8 store planes, chunk 9 stores out0.
// grid (200, cnb)  block 256 (4 waves = 8 quads)
// ---------------------------------------------------------------------------
__global__ __launch_bounds__(256) void scores_kernel(
    const bf16* __restrict__ qt, const bf16* __restrict__ kt,
    float* __restrict__ scores, float* __restrict__ out0, int b0)
{
    const int tid   = threadIdx.x;
    const int wave  = tid >> 6;
    const int lane  = tid & 63;
    const int ql    = lane & 1;           // quad within wave group
    const int chunk = lane >> 1;          // 8-channel chunk 0..31

    const int qi = blockIdx.x * 8 + wave * 2 + ql;     // quad index [0,1600)
    const int bl = blockIdx.y;
    const int b  = b0 + bl;
    const int n0 = qi * 4;
    const int r  = qi / 20;               // 20 quads per image row
    const int p0 = n0 - r * WW;           // col of px0 (multiple of 4)

    const unsigned short* qp = (const unsigned short*)(qt + (size_t)bl * NPIX * CH)
                               + (size_t)chunk * 8 * NPIX;
    const unsigned short* kp = (const unsigned short*)(kt + (size_t)bl * NPIX * CH)
                               + (size_t)chunk * 8 * NPIX;

    const int rbm = max(r - 1, 0) * WW;
    const int rb0 = r * WW;
    const int rbp = min(r + 1, HH - 1) * WW;
    const bool eL = (p0 == 0), eR = (p0 == 76);

    float acc[4][9];
    #pragma unroll
    for (int px = 0; px < 4; ++px)
        #pragma unroll
        for (int j = 0; j < 9; ++j) acc[px][j] = 0.f;

    #pragma unroll
    for (int c = 0; c < 8; ++c) {
        const size_t cb = (size_t)c * NPIX;
        const ushort4 qv = *(const ushort4*)(qp + cb + n0);
        const float qf0 = b2f(qv.x), qf1 = b2f(qv.y), qf2 = b2f(qv.z), qf3 = b2f(qv.w);

        #pragma unroll
        for (int dr = 0; dr < 3; ++dr) {
            const int rb = (dr == 0) ? rbm : (dr == 1) ? rb0 : rbp;
            // 16B load covering cols p0-2 .. p0+5 (4B-aligned; OOB edges
            // cancelled exactly by the clamp corrections below)
            const short8 kw = *(const short8*)(kp + cb + rb + p0 - 2);
            const float w3 = b2f((unsigned short)kw[1]);
            const float w4 = b2f((unsigned short)kw[2]);
            const float w5 = b2f((unsigned short)kw[3]);
            const float w6 = b2f((unsigned short)kw[4]);
            const float w7 = b2f((unsigned short)kw[5]);
            const float w8 = b2f((unsigned short)kw[6]);

            acc[0][dr*3+0] += qf0 * w3;
            acc[0][dr*3+1] += qf0 * w4;
            acc[0][dr*3+2] += qf0 * w5;
            acc[1][dr*3+0] += qf1 * w4;
            acc[1][dr*3+1] += qf1 * w5;
            acc[1][dr*3+2] += qf1 * w6;
            acc[2][dr*3+0] += qf2 * w5;
            acc[2][dr*3+1] += qf2 * w6;
            acc[2][dr*3+2] += qf2 * w7;
            acc[3][dr*3+0] += qf3 * w6;
            acc[3][dr*3+1] += qf3 * w7;
            acc[3][dr*3+2] += qf3 * w8;
            if (eL) acc[0][dr*3+0] += qf0 * (w4 - w3);   // clamp col -1 -> 0
            if (eR) acc[3][dr*3+2] += qf3 * (w7 - w8);   // clamp col 80 -> 79
        }
    }

    // combine the 32 c-chunks: butterfly across lanes l^2,4,8,16,32
    #pragma unroll
    for (int px = 0; px < 4; ++px)
        #pragma unroll
        for (int j = 0; j < 9; ++j) {
            float v = acc[px][j];
            v += __shfl_xor(v, 2,  64);
            v += __shfl_xor(v, 4,  64);
            v += __shfl_xor(v, 8,  64);
            v += __shfl_xor(v, 16, 64);
            v += __shfl_xor(v, 32, 64);
            acc[px][j] = v;
        }

    // distributed stores: chunk j (j<9) writes plane j; chunk 9 writes out0.
    float* sp = scores + (size_t)bl * 9 * NPIX;
    if (chunk < 9) {
        float4 v = { acc[0][chunk], acc[1][chunk], acc[2][chunk], acc[3][chunk] };
        *(float4*)(sp + (size_t)chunk * NPIX + n0) = v;
    } else if (chunk == 9) {
        float ssum[4];
        #pragma unroll
        for (int px = 0; px < 4; ++px) {
            float s = 0.f;
            #pragma unroll
            for (int j = 0; j < 9; ++j) s += acc[px][j];
            ssum[px] = s;
        }
        float* op = out0 + ((size_t)b * NPIX + n0) * 2;
        float4 o0v = { acc[0][4], (ssum[0] - acc[0][4]) * 0.125f,
                       acc[1][4], (ssum[1] - acc[1][4]) * 0.125f };
        float4 o1v = { acc[2][4], (ssum[2] - acc[2][4]) * 0.125f,
                       acc[3][4], (ssum[3] - acc[3][4]) * 0.125f };
        *(float4*)(op)     = o0v;
        *(float4*)(op + 4) = o1v;
    }
}

// ---------------------------------------------------------------------------
// Kernel 4 (v3): fused new_v + residual + LayerNorm, TWO channels per block.
// x float4 loads prefetched up-front (fly under vt LDS staging).
// grid (CH/2, cnb)  block 320
// ---------------------------------------------------------------------------
__global__ __launch_bounds__(320) void newv_ln(
    const float* __restrict__ x, const bf16* __restrict__ vt,
    const float* __restrict__ scores, float* __restrict__ xout, int b0)
{
    __shared__ __align__(16) unsigned short lds_v[2][NPIX];
    __shared__ float rsum[5][2], rsq[5][2];

    const int cp2 = blockIdx.x;            // channel pair
    const int bl  = blockIdx.y;
    const int b   = b0 + bl;
    const int tid = threadIdx.x;

    const int4* vsrc = (const int4*)(vt + ((size_t)bl * CH + cp2 * 2) * NPIX);
    const float* xrow0 = x + ((size_t)b * CH + cp2 * 2) * NPIX;
    const float* xrow1 = xrow0 + NPIX;
    const float* sb    = scores + (size_t)bl * 9 * NPIX;

    float4 xv0[5], xv1[5];
    #pragma unroll
    for (int i = 0; i < 5; ++i) {
        const int n0 = (tid + i * 320) * 4;
        xv0[i] = *(const float4*)(xrow0 + n0);
        xv1[i] = *(const float4*)(xrow1 + n0);
    }

    #pragma unroll
    for (int i = 0; i < 5; ++i)
        ((int4*)lds_v)[tid + i * 320] = vsrc[tid + i * 320];
    __syncthreads();

    float val0[20], val1[20];
    float sum0 = 0.f, sq0 = 0.f, sum1 = 0.f, sq1 = 0.f;
    #pragma unroll
    for (int it = 0; it < 5; ++it) {
        const int p   = tid + it * 320;
        const int n0  = p * 4;
        const int r   = p / 20;
        const int c0  = (p % 20) * 4;

        const int rm = max(r - 1, 0) * WW;
        const int r0 = r * WW;
        const int rp = min(r + 1, HH - 1) * WW;

        float4 s[9];
        #pragma unroll
        for (int j = 0; j < 9; ++j)
            s[j] = *(const float4*)(sb + (size_t)j * NPIX + n0);

        const int cA = max(c0 - 1, 0);
        const int cF = min(c0 + 4, WW - 1);

        #pragma unroll
        for (int pl = 0; pl < 2; ++pl) {
            const unsigned short* lv = lds_v[pl];
            float vm[6], v0[6], vp[6];
            {
                const ushort4 a = *(const ushort4*)&lv[rm + c0];
                vm[1] = b2f(a.x); vm[2] = b2f(a.y); vm[3] = b2f(a.z); vm[4] = b2f(a.w);
                vm[0] = b2f(lv[rm + cA]); vm[5] = b2f(lv[rm + cF]);
            }
            {
                const ushort4 a = *(const ushort4*)&lv[r0 + c0];
                v0[1] = b2f(a.x); v0[2] = b2f(a.y); v0[3] = b2f(a.z); v0[4] = b2f(a.w);
                v0[0] = b2f(lv[r0 + cA]); v0[5] = b2f(lv[r0 + cF]);
            }
            {
                const ushort4 a = *(const ushort4*)&lv[rp + c0];
                vp[1] = b2f(a.x); vp[2] = b2f(a.y); vp[3] = b2f(a.z); vp[4] = b2f(a.w);
                vp[0] = b2f(lv[rp + cA]); vp[5] = b2f(lv[rp + cF]);
            }

            const float4 xin = pl ? xv1[it] : xv0[it];
            #pragma unroll
            for (int px = 0; px < 4; ++px) {
                float a;
                a  = ((const float*)&s[0])[px] * vm[px]
                   + ((const float*)&s[1])[px] * vm[px + 1]
                   + ((const float*)&s[2])[px] * vm[px + 2];
                a += ((const float*)&s[3])[px] * v0[px]
                   + ((const float*)&s[4])[px] * v0[px + 1]
                   + ((const float*)&s[5])[px] * v0[px + 2];
                a += ((const float*)&s[6])[px] * vp[px]
                   + ((const float*)&s[7])[px] * vp[px + 1]
                   + ((const float*)&s[8])[px] * vp[px + 2];
                const float vv = ((const float*)&xin)[px] + a;
                if (pl == 0) { val0[it * 4 + px] = vv; sum0 += vv; sq0 += vv * vv; }
                else         { val1[it * 4 + px] = vv; sum1 += vv; sq1 += vv * vv; }
            }
        }
    }

    #pragma unroll
    for (int off = 32; off >= 1; off >>= 1) {
        sum0 += __shfl_xor(sum0, off, 64);
        sq0  += __shfl_xor(sq0,  off, 64);
        sum1 += __shfl_xor(sum1, off, 64);
        sq1  += __shfl_xor(sq1,  off, 64);
    }
    const int wave = tid >> 6, lane = tid & 63;
    if (lane == 0) {
        rsum[wave][0] = sum0; rsq[wave][0] = sq0;
        rsum[wave][1] = sum1; rsq[wave][1] = sq1;
    }
    __syncthreads();
    sum0 = rsum[0][0] + rsum[1][0] + rsum[2][0] + rsum[3][0] + rsum[4][0];
    sq0  = rsq[0][0]  + rsq[1][0]  + rsq[2][0]  + rsq[3][0]  + rsq[4][0];
    sum1 = rsum[0][1] + rsum[1][1] + rsum[2][1] + rsum[3][1] + rsum[4][1];
    sq1  = rsq[0][1]  + rsq[1][1]  + rsq[2][1]  + rsq[3][1]  + rsq[4][1];

    const float mu0   = sum0 * (1.f / NPIX);
    const float var0  = sq0 * (1.f / NPIX) - mu0 * mu0;
    const float rstd0 = rsqrtf(var0 + 1e-5f);
    const float mu1   = sum1 * (1.f / NPIX);
    const float var1  = sq1 * (1.f / NPIX) - mu1 * mu1;
    const float rstd1 = rsqrtf(var1 + 1e-5f);

    float* orow0 = xout + ((size_t)b * CH + cp2 * 2) * NPIX;
    float* orow1 = orow0 + NPIX;
    #pragma unroll
    for (int it = 0; it < 5; ++it) {
        const int n0 = (tid + it * 320) * 4;
        float4 o0, o1;
        #pragma unroll
        for (int px = 0; px < 4; ++px) {
            ((float*)&o0)[px] = (val0[it * 4 + px] - mu0) * rstd0;
            ((float*)&o1)[px] = (val1[it * 4 + px] - mu1) * rstd1;
        }
        *(float4*)(orow0 + n0) = o0;
        *(float4*)(orow1 + n0) = o1;
    }
}

// ---------------------------------------------------------------------------
extern "C" void kernel_launch(void* const* d_in, const int* in_sizes, int n_in,
                              void* d_out, int out_size, void* d_ws, size_t ws_size,
                              hipStream_t stream)
{
    const float* x  = (const float*)d_in[0];
    const float* Wq = (const float*)d_in[1];
    const float* bq = (const float*)d_in[2];
    const float* Wk = (const float*)d_in[3];
    const float* bk = (const float*)d_in[4];
    const float* Wv = (const float*)d_in[5];
    const float* bv = (const float*)d_in[6];

    float* out0 = (float*)d_out;                       // [B][N][2]
    float* xout = out0 + (size_t)BATCH * NPIX * 2;     // [B][C][N]

    char* ws = (char*)d_ws;
    bf16* Wb = (bf16*)ws;
    ws += (size_t)3 * CH * CH * sizeof(bf16);          // 384 KiB

    const size_t fBF = (size_t)NPIX * CH * sizeof(bf16);   // 3.28 MB
    const size_t fSC = (size_t)NPIX * 9 * sizeof(float);   // 230 KB
    const size_t perBatch = 4 * fBF + fSC;                 // ~13.3 MB

    size_t avail = ws_size - ((size_t)3 * CH * CH * sizeof(bf16));
    int NB = (int)(avail / perBatch);
    if (NB < 1)  NB = 1;
    if (NB > BATCH) NB = BATCH;

    bf16*  xt  = (bf16*)ws;
    bf16*  qtb = (bf16*)(ws + (size_t)NB * fBF);
    bf16*  ktb = (bf16*)(ws + (size_t)NB * fBF * 2);
    bf16*  vtb = (bf16*)(ws + (size_t)NB * fBF * 3);
    float* sc  = (float*)(ws + (size_t)NB * fBF * 4);

    convert_w<<<dim3(CH * CH / 256, 3), 256, 0, stream>>>(Wq, Wk, Wv, Wb);

    for (int b0 = 0; b0 < BATCH; b0 += NB) {
        const int cnb = (BATCH - b0 < NB) ? (BATCH - b0) : NB;

        transpose_cast<<<dim3(NPIX / 64, CH / 64, cnb), 256, 0, stream>>>(x, xt, b0);

        qkv_mfma<<<dim3(NPIX / 128, CH / 128, cnb), 256, 0, stream>>>(
            xt, Wb, bq, bk, bv, qtb, ktb, vtb);

        scores_kernel<<<dim3(200, cnb), 256, 0, stream>>>(qtb, ktb, sc, out0, b0);

        newv_ln<<<dim3(CH / 2, cnb), 320, 0, stream>>>(x, vtb, sc, xout, b0);
    }
}

// Round 18
// 272.806 us; speedup vs baseline: 1.8790x; 1.8790x over previous
//
#include <hip/hip_runtime.h>
#include <hip/hip_bf16.h>

using f32x4  = __attribute__((ext_vector_type(4))) float;
using short8 = __attribute__((ext_vector_type(8))) short;
using bf16   = __hip_bfloat16;

constexpr int BATCH = 16;
constexpr int CH    = 256;
constexpr int HH    = 80;
constexpr int WW    = 80;
constexpr int NPIX  = HH * WW;   // 6400

__device__ __forceinline__ float b2f(unsigned short u) {
    union { unsigned int i; float f; } x;
    x.i = ((unsigned int)u) << 16;
    return x.f;
}

// global -> LDS direct copy, 16B per lane.
typedef __attribute__((address_space(3))) void  lds_void;
typedef __attribute__((address_space(1))) const void glb_void;
__device__ __forceinline__ void glds16(const void* g, void* l) {
    __builtin_amdgcn_global_load_lds((glb_void*)(unsigned long long)g,
                                     (lds_void*)(unsigned int)(unsigned long long)l,
                                     16, 0, 0);
}

// ---------------------------------------------------------------------------
// Kernel 0: convert weights fp32 -> bf16.
// ---------------------------------------------------------------------------
__global__ __launch_bounds__(256) void convert_w(
    const float* __restrict__ Wq, const float* __restrict__ Wk,
    const float* __restrict__ Wv, bf16* __restrict__ Wb)
{
    const int elem = blockIdx.x * 256 + threadIdx.x;
    const int mat  = blockIdx.y;
    const float* src = (mat == 0) ? Wq : (mat == 1) ? Wk : Wv;
    Wb[(size_t)mat * CH * CH + elem] = __float2bfloat16(src[elem]);
}

// ---------------------------------------------------------------------------
// Kernel 1: x [b][c][n] fp32 -> x_t [bl][n][c] bf16 (tiled transpose,
// packed ushort4 stores).  At HBM BW floor (157 MB ~ 25 us).
// ---------------------------------------------------------------------------
__global__ __launch_bounds__(256) void transpose_cast(
    const float* __restrict__ x, bf16* __restrict__ xt, int b0)
{
    __shared__ float t[64][65];
    const int b  = b0 + blockIdx.z;
    const int n0 = blockIdx.x * 64;
    const int c0 = blockIdx.y * 64;
    const float* xb = x + (size_t)b * CH * NPIX;
    const int tid = threadIdx.x;

    {
        const int nl  = tid & 63;
        const int cl0 = tid >> 6;
        #pragma unroll
        for (int i = 0; i < 16; ++i) {
            const int cl = cl0 + i * 4;
            t[cl][nl] = xb[(size_t)(c0 + cl) * NPIX + n0 + nl];
        }
    }
    __syncthreads();
    {
        bf16* xtb = xt + (size_t)blockIdx.z * NPIX * CH;
        const int cp  = (tid & 15) * 4;
        const int nl0 = tid >> 4;
        #pragma unroll
        for (int i = 0; i < 4; ++i) {
            const int nl = nl0 + i * 16;
            ushort4 pk;
            #pragma unroll
            for (int j = 0; j < 4; ++j) {
                const bf16 h = __float2bfloat16(t[cp + j][nl]);
                ((unsigned short*)&pk)[j] = *(const unsigned short*)&h;
            }
            *(ushort4*)(xtb + (size_t)(n0 + nl) * CH + c0 + cp) = pk;
        }
    }
}

// ---------------------------------------------------------------------------
// Kernel 2 (r8 best): MFMA GEMM, A-resident + q/k/v fused.
// Empirical best across r8-r15 variants (93.5 us).
// grid (NPIX/128, CH/128, cnb)  block 256 (4 waves, each 64x64)
// ---------------------------------------------------------------------------
__global__ __launch_bounds__(256, 2) void qkv_mfma(
    const bf16* __restrict__ xt, const bf16* __restrict__ Wb,
    const float* __restrict__ bq, const float* __restrict__ bk,
    const float* __restrict__ bv,
    bf16* __restrict__ qt, bf16* __restrict__ kt, bf16* __restrict__ vt)
{
    const int bl = blockIdx.z;
    const int n0 = blockIdx.x * 128;
    const int o0 = blockIdx.y * 128;
    const bf16* A = xt + (size_t)bl * NPIX * CH;

    __shared__ char As[128 * 512];     // 64 KB, full K=256
    __shared__ char Bs[2][128 * 64];   // 16 KB, double-buffered

    const int tid = threadIdx.x;
    const int wv  = tid >> 6, ln = tid & 63;
    const int wr  = wv >> 1,  wc = wv & 1;
    const int lm  = ln & 15,  lk = ln >> 4;

    #pragma unroll
    for (int t = 0; t < 16; ++t) {
        const int idx = t * 256 + tid;           // 0..4095 (16B units)
        const int row = idx >> 5, pos = idx & 31;
        const int chk = pos ^ (row & 7);
        glds16(A + (size_t)(n0 + row) * CH + chk * 8, &As[idx * 16]);
    }

    auto stageB = [&](int buf, const bf16* Wm, int k0) {
        #pragma unroll
        for (int it = 0; it < 2; ++it) {
            const int idx = it * 256 + tid;      // 0..511
            const int row = idx >> 2, pos = idx & 3;
            const int chk = pos ^ ((row >> 1) & 3);
            glds16(Wm + (size_t)(o0 + row) * CH + k0 + chk * 8, &Bs[buf][idx * 16]);
        }
    };

    stageB(0, Wb, 0);
    int buf = 0;

    bf16* const outs[3] = { qt + (size_t)bl * CH * NPIX,
                            kt + (size_t)bl * CH * NPIX,
                            vt + (size_t)bl * CH * NPIX };
    const float* const biases[3] = { bq, bk, bv };

    #pragma unroll
    for (int m = 0; m < 3; ++m) {
        f32x4 acc[4][4];
        #pragma unroll
        for (int i = 0; i < 4; ++i)
            #pragma unroll
            for (int j = 0; j < 4; ++j)
                #pragma unroll
                for (int r = 0; r < 4; ++r) acc[i][j][r] = 0.f;

        #pragma unroll
        for (int t = 0; t < 8; ++t) {
            __syncthreads();
            const int s = m * 8 + t;
            if (s < 23) {
                const int ns = s + 1;
                stageB(buf ^ 1, Wb + (size_t)(ns >> 3) * CH * CH, (ns & 7) * 32);
            }

            short8 afr[4], bfr[4];
            #pragma unroll
            for (int i = 0; i < 4; ++i) {
                const int row = wr * 64 + i * 16 + lm;
                const int chunk = (t * 4 + lk) ^ (row & 7);
                afr[i] = *(const short8*)&As[row * 512 + chunk * 16];
            }
            #pragma unroll
            for (int j = 0; j < 4; ++j) {
                const int row = wc * 64 + j * 16 + lm;
                const int chk = lk ^ ((row >> 1) & 3);
                bfr[j] = *(const short8*)&Bs[buf][row * 64 + chk * 16];
            }
            #pragma unroll
            for (int i = 0; i < 4; ++i)
                #pragma unroll
                for (int j = 0; j < 4; ++j)
                    acc[i][j] = __builtin_amdgcn_mfma_f32_16x16x32_bf16(
                        afr[i], bfr[j], acc[i][j], 0, 0, 0);
            buf ^= 1;
        }

        bf16* out = outs[m];
        const float* bias = biases[m];
        #pragma unroll
        for (int j = 0; j < 4; ++j) {
            const int o = o0 + wc * 64 + j * 16 + lm;
            const float bs = bias[o];
            #pragma unroll
            for (int i = 0; i < 4; ++i) {
                const int nb = n0 + wr * 64 + i * 16 + lk * 4;
                ushort4 pk;
                #pragma unroll
                for (int r = 0; r < 4; ++r) {
                    const bf16 h = __float2bfloat16(acc[i][j][r] + bs);
                    ((unsigned short*)&pk)[r] = *(const unsigned short*)&h;
                }
                *(ushort4*)(out + (size_t)o * NPIX + nb) = pk;
            }
        }
    }
}

// ---------------------------------------------------------------------------
// Kernel 3: scores v5 — wave = 4 quads x 16 c-chunks (16 ch each).
// Butterfly shfl_xor(4,8,16,32); stores distributed over 10 chunk groups.
// v6 (32 chunks x 2 quads) destroyed coalescing (FETCH 7.5x) — do not split
// below 4-quad/64B-contiguous groups.
// grid (100, cnb)  block 256 (4 waves = 16 quads)
// ---------------------------------------------------------------------------
__global__ __launch_bounds__(256) void scores_kernel(
    const bf16* __restrict__ qt, const bf16* __restrict__ kt,
    float* __restrict__ scores, float* __restrict__ out0, int b0)
{
    const int tid   = threadIdx.x;
    const int wave  = tid >> 6;
    const int lane  = tid & 63;
    const int ql    = lane & 3;           // quad within wave group
    const int chunk = lane >> 2;          // 16-channel chunk 0..15

    const int qi = blockIdx.x * 16 + wave * 4 + ql;    // quad index [0,1600)
    const int bl = blockIdx.y;
    const int b  = b0 + bl;
    const int n0 = qi * 4;
    const int r  = qi / 20;               // 20 quads per image row
    const int p0 = n0 - r * WW;           // col of px0 (multiple of 4)

    const unsigned short* qp = (const unsigned short*)(qt + (size_t)bl * NPIX * CH)
                               + (size_t)chunk * 16 * NPIX;
    const unsigned short* kp = (const unsigned short*)(kt + (size_t)bl * NPIX * CH)
                               + (size_t)chunk * 16 * NPIX;

    const int rbm = max(r - 1, 0) * WW;
    const int rb0 = r * WW;
    const int rbp = min(r + 1, HH - 1) * WW;
    const bool eL = (p0 == 0), eR = (p0 == 76);

    float acc[4][9];
    #pragma unroll
    for (int px = 0; px < 4; ++px)
        #pragma unroll
        for (int j = 0; j < 9; ++j) acc[px][j] = 0.f;

    #pragma unroll 4
    for (int c = 0; c < 16; ++c) {
        const size_t cb = (size_t)c * NPIX;
        const ushort4 qv = *(const ushort4*)(qp + cb + n0);
        const float qf0 = b2f(qv.x), qf1 = b2f(qv.y), qf2 = b2f(qv.z), qf3 = b2f(qv.w);

        #pragma unroll
        for (int dr = 0; dr < 3; ++dr) {
            const int rb = (dr == 0) ? rbm : (dr == 1) ? rb0 : rbp;
            const short8 kw = *(const short8*)(kp + cb + rb + p0 - 2);
            const float w3 = b2f((unsigned short)kw[1]);
            const float w4 = b2f((unsigned short)kw[2]);
            const float w5 = b2f((unsigned short)kw[3]);
            const float w6 = b2f((unsigned short)kw[4]);
            const float w7 = b2f((unsigned short)kw[5]);
            const float w8 = b2f((unsigned short)kw[6]);

            acc[0][dr*3+0] += qf0 * w3;
            acc[0][dr*3+1] += qf0 * w4;
            acc[0][dr*3+2] += qf0 * w5;
            acc[1][dr*3+0] += qf1 * w4;
            acc[1][dr*3+1] += qf1 * w5;
            acc[1][dr*3+2] += qf1 * w6;
            acc[2][dr*3+0] += qf2 * w5;
            acc[2][dr*3+1] += qf2 * w6;
            acc[2][dr*3+2] += qf2 * w7;
            acc[3][dr*3+0] += qf3 * w6;
            acc[3][dr*3+1] += qf3 * w7;
            acc[3][dr*3+2] += qf3 * w8;
            if (eL) acc[0][dr*3+0] += qf0 * (w4 - w3);   // clamp col -1 -> 0
            if (eR) acc[3][dr*3+2] += qf3 * (w7 - w8);   // clamp col 80 -> 79
        }
    }

    #pragma unroll
    for (int px = 0; px < 4; ++px)
        #pragma unroll
        for (int j = 0; j < 9; ++j) {
            float v = acc[px][j];
            v += __shfl_xor(v, 4,  64);
            v += __shfl_xor(v, 8,  64);
            v += __shfl_xor(v, 16, 64);
            v += __shfl_xor(v, 32, 64);
            acc[px][j] = v;
        }

    float* sp = scores + (size_t)bl * 9 * NPIX;
    if (chunk < 9) {
        float4 v = { acc[0][chunk], acc[1][chunk], acc[2][chunk], acc[3][chunk] };
        *(float4*)(sp + (size_t)chunk * NPIX + n0) = v;
    } else if (chunk == 9) {
        float ssum[4];
        #pragma unroll
        for (int px = 0; px < 4; ++px) {
            float s = 0.f;
            #pragma unroll
            for (int j = 0; j < 9; ++j) s += acc[px][j];
            ssum[px] = s;
        }
        float* op = out0 + ((size_t)b * NPIX + n0) * 2;
        float4 o0v = { acc[0][4], (ssum[0] - acc[0][4]) * 0.125f,
                       acc[1][4], (ssum[1] - acc[1][4]) * 0.125f };
        float4 o1v = { acc[2][4], (ssum[2] - acc[2][4]) * 0.125f,
                       acc[3][4], (ssum[3] - acc[3][4]) * 0.125f };
        *(float4*)(op)     = o0v;
        *(float4*)(op + 4) = o1v;
    }
}

// ---------------------------------------------------------------------------
// Kernel 4 (v3): fused new_v + residual + LayerNorm, TWO channels per block.
// x float4 loads prefetched up-front (fly under vt LDS staging).
// grid (CH/2, cnb)  block 320
// ---------------------------------------------------------------------------
__global__ __launch_bounds__(320) void newv_ln(
    const float* __restrict__ x, const bf16* __restrict__ vt,
    const float* __restrict__ scores, float* __restrict__ xout, int b0)
{
    __shared__ __align__(16) unsigned short lds_v[2][NPIX];
    __shared__ float rsum[5][2], rsq[5][2];

    const int cp2 = blockIdx.x;            // channel pair
    const int bl  = blockIdx.y;
    const int b   = b0 + bl;
    const int tid = threadIdx.x;

    const int4* vsrc = (const int4*)(vt + ((size_t)bl * CH + cp2 * 2) * NPIX);
    const float* xrow0 = x + ((size_t)b * CH + cp2 * 2) * NPIX;
    const float* xrow1 = xrow0 + NPIX;
    const float* sb    = scores + (size_t)bl * 9 * NPIX;

    float4 xv0[5], xv1[5];
    #pragma unroll
    for (int i = 0; i < 5; ++i) {
        const int n0 = (tid + i * 320) * 4;
        xv0[i] = *(const float4*)(xrow0 + n0);
        xv1[i] = *(const float4*)(xrow1 + n0);
    }

    #pragma unroll
    for (int i = 0; i < 5; ++i)
        ((int4*)lds_v)[tid + i * 320] = vsrc[tid + i * 320];
    __syncthreads();

    float val0[20], val1[20];
    float sum0 = 0.f, sq0 = 0.f, sum1 = 0.f, sq1 = 0.f;
    #pragma unroll
    for (int it = 0; it < 5; ++it) {
        const int p   = tid + it * 320;
        const int n0  = p * 4;
        const int r   = p / 20;
        const int c0  = (p % 20) * 4;

        const int rm = max(r - 1, 0) * WW;
        const int r0 = r * WW;
        const int rp = min(r + 1, HH - 1) * WW;

        float4 s[9];
        #pragma unroll
        for (int j = 0; j < 9; ++j)
            s[j] = *(const float4*)(sb + (size_t)j * NPIX + n0);

        const int cA = max(c0 - 1, 0);
        const int cF = min(c0 + 4, WW - 1);

        #pragma unroll
        for (int pl = 0; pl < 2; ++pl) {
            const unsigned short* lv = lds_v[pl];
            float vm[6], v0[6], vp[6];
            {
                const ushort4 a = *(const ushort4*)&lv[rm + c0];
                vm[1] = b2f(a.x); vm[2] = b2f(a.y); vm[3] = b2f(a.z); vm[4] = b2f(a.w);
                vm[0] = b2f(lv[rm + cA]); vm[5] = b2f(lv[rm + cF]);
            }
            {
                const ushort4 a = *(const ushort4*)&lv[r0 + c0];
                v0[1] = b2f(a.x); v0[2] = b2f(a.y); v0[3] = b2f(a.z); v0[4] = b2f(a.w);
                v0[0] = b2f(lv[r0 + cA]); v0[5] = b2f(lv[r0 + cF]);
            }
            {
                const ushort4 a = *(const ushort4*)&lv[rp + c0];
                vp[1] = b2f(a.x); vp[2] = b2f(a.y); vp[3] = b2f(a.z); vp[4] = b2f(a.w);
                vp[0] = b2f(lv[rp + cA]); vp[5] = b2f(lv[rp + cF]);
            }

            const float4 xin = pl ? xv1[it] : xv0[it];
            #pragma unroll
            for (int px = 0; px < 4; ++px) {
                float a;
                a  = ((const float*)&s[0])[px] * vm[px]
                   + ((const float*)&s[1])[px] * vm[px + 1]
                   + ((const float*)&s[2])[px] * vm[px + 2];
                a += ((const float*)&s[3])[px] * v0[px]
                   + ((const float*)&s[4])[px] * v0[px + 1]
                   + ((const float*)&s[5])[px] * v0[px + 2];
                a += ((const float*)&s[6])[px] * vp[px]
                   + ((const float*)&s[7])[px] * vp[px + 1]
                   + ((const float*)&s[8])[px] * vp[px + 2];
                const float vv = ((const float*)&xin)[px] + a;
                if (pl == 0) { val0[it * 4 + px] = vv; sum0 += vv; sq0 += vv * vv; }
                else         { val1[it * 4 + px] = vv; sum1 += vv; sq1 += vv * vv; }
            }
        }
    }

    #pragma unroll
    for (int off = 32; off >= 1; off >>= 1) {
        sum0 += __shfl_xor(sum0, off, 64);
        sq0  += __shfl_xor(sq0,  off, 64);
        sum1 += __shfl_xor(sum1, off, 64);
        sq1  += __shfl_xor(sq1,  off, 64);
    }
    const int wave = tid >> 6, lane = tid & 63;
    if (lane == 0) {
        rsum[wave][0] = sum0; rsq[wave][0] = sq0;
        rsum[wave][1] = sum1; rsq[wave][1] = sq1;
    }
    __syncthreads();
    sum0 = rsum[0][0] + rsum[1][0] + rsum[2][0] + rsum[3][0] + rsum[4][0];
    sq0  = rsq[0][0]  + rsq[1][0]  + rsq[2][0]  + rsq[3][0]  + rsq[4][0];
    sum1 = rsum[0][1] + rsum[1][1] + rsum[2][1] + rsum[3][1] + rsum[4][1];
    sq1  = rsq[0][1]  + rsq[1][1]  + rsq[2][1]  + rsq[3][1]  + rsq[4][1];

    const float mu0   = sum0 * (1.f / NPIX);
    const float var0  = sq0 * (1.f / NPIX) - mu0 * mu0;
    const float rstd0 = rsqrtf(var0 + 1e-5f);
    const float mu1   = sum1 * (1.f / NPIX);
    const float var1  = sq1 * (1.f / NPIX) - mu1 * mu1;
    const float rstd1 = rsqrtf(var1 + 1e-5f);

    float* orow0 = xout + ((size_t)b * CH + cp2 * 2) * NPIX;
    float* orow1 = orow0 + NPIX;
    #pragma unroll
    for (int it = 0; it < 5; ++it) {
        const int n0 = (tid + it * 320) * 4;
        float4 o0, o1;
        #pragma unroll
        for (int px = 0; px < 4; ++px) {
            ((float*)&o0)[px] = (val0[it * 4 + px] - mu0) * rstd0;
            ((float*)&o1)[px] = (val1[it * 4 + px] - mu1) * rstd1;
        }
        *(float4*)(orow0 + n0) = o0;
        *(float4*)(orow1 + n0) = o1;
    }
}

// ---------------------------------------------------------------------------
extern "C" void kernel_launch(void* const* d_in, const int* in_sizes, int n_in,
                              void* d_out, int out_size, void* d_ws, size_t ws_size,
                              hipStream_t stream)
{
    const float* x  = (const float*)d_in[0];
    const float* Wq = (const float*)d_in[1];
    const float* bq = (const float*)d_in[2];
    const float* Wk = (const float*)d_in[3];
    const float* bk = (const float*)d_in[4];
    const float* Wv = (const float*)d_in[5];
    const float* bv = (const float*)d_in[6];

    float* out0 = (float*)d_out;                       // [B][N][2]
    float* xout = out0 + (size_t)BATCH * NPIX * 2;     // [B][C][N]

    char* ws = (char*)d_ws;
    bf16* Wb = (bf16*)ws;
    ws += (size_t)3 * CH * CH * sizeof(bf16);          // 384 KiB

    const size_t fBF = (size_t)NPIX * CH * sizeof(bf16);   // 3.28 MB
    const size_t fSC = (size_t)NPIX * 9 * sizeof(float);   // 230 KB
    const size_t perBatch = 4 * fBF + fSC;                 // ~13.3 MB

    size_t avail = ws_size - ((size_t)3 * CH * CH * sizeof(bf16));
    int NB = (int)(avail / perBatch);
    if (NB < 1)  NB = 1;
    if (NB > BATCH) NB = BATCH;

    bf16*  xt  = (bf16*)ws;
    bf16*  qtb = (bf16*)(ws + (size_t)NB * fBF);
    bf16*  ktb = (bf16*)(ws + (size_t)NB * fBF * 2);
    bf16*  vtb = (bf16*)(ws + (size_t)NB * fBF * 3);
    float* sc  = (float*)(ws + (size_t)NB * fBF * 4);

    convert_w<<<dim3(CH * CH / 256, 3), 256, 0, stream>>>(Wq, Wk, Wv, Wb);

    for (int b0 = 0; b0 < BATCH; b0 += NB) {
        const int cnb = (BATCH - b0 < NB) ? (BATCH - b0) : NB;

        transpose_cast<<<dim3(NPIX / 64, CH / 64, cnb), 256, 0, stream>>>(x, xt, b0);

        qkv_mfma<<<dim3(NPIX / 128, CH / 128, cnb), 256, 0, stream>>>(
            xt, Wb, bq, bk, bv, qtb, ktb, vtb);

        scores_kernel<<<dim3(100, cnb), 256, 0, stream>>>(qtb, ktb, sc, out0, b0);

        newv_ln<<<dim3(CH / 2, cnb), 320, 0, stream>>>(x, vtb, sc, xout, b0);
    }
}

// Round 19
// 269.385 us; speedup vs baseline: 1.9029x; 1.0127x over previous
//
#include <hip/hip_runtime.h>
#include <hip/hip_bf16.h>

using f32x4  = __attribute__((ext_vector_type(4))) float;
using short8 = __attribute__((ext_vector_type(8))) short;
using bf16   = __hip_bfloat16;

constexpr int BATCH = 16;
constexpr int CH    = 256;
constexpr int HH    = 80;
constexpr int WW    = 80;
constexpr int NPIX  = HH * WW;   // 6400

__device__ __forceinline__ float b2f(unsigned short u) {
    union { unsigned int i; float f; } x;
    x.i = ((unsigned int)u) << 16;
    return x.f;
}

// global -> LDS direct copy, 16B per lane.
typedef __attribute__((address_space(3))) void  lds_void;
typedef __attribute__((address_space(1))) const void glb_void;
__device__ __forceinline__ void glds16(const void* g, void* l) {
    __builtin_amdgcn_global_load_lds((glb_void*)(unsigned long long)g,
                                     (lds_void*)(unsigned int)(unsigned long long)l,
                                     16, 0, 0);
}

// ---------------------------------------------------------------------------
// Kernel 0: convert weights fp32 -> bf16.
// ---------------------------------------------------------------------------
__global__ __launch_bounds__(256) void convert_w(
    const float* __restrict__ Wq, const float* __restrict__ Wk,
    const float* __restrict__ Wv, bf16* __restrict__ Wb)
{
    const int elem = blockIdx.x * 256 + threadIdx.x;
    const int mat  = blockIdx.y;
    const float* src = (mat == 0) ? Wq : (mat == 1) ? Wk : Wv;
    Wb[(size_t)mat * CH * CH + elem] = __float2bfloat16(src[elem]);
}

// ---------------------------------------------------------------------------
// Kernel 1: x [b][c][n] fp32 -> x_t [bl][n][c] bf16 (tiled transpose,
// packed ushort4 stores).
// ---------------------------------------------------------------------------
__global__ __launch_bounds__(256) void transpose_cast(
    const float* __restrict__ x, bf16* __restrict__ xt, int b0)
{
    __shared__ float t[64][65];
    const int b  = b0 + blockIdx.z;
    const int n0 = blockIdx.x * 64;
    const int c0 = blockIdx.y * 64;
    const float* xb = x + (size_t)b * CH * NPIX;
    const int tid = threadIdx.x;

    {
        const int nl  = tid & 63;
        const int cl0 = tid >> 6;
        #pragma unroll
        for (int i = 0; i < 16; ++i) {
            const int cl = cl0 + i * 4;
            t[cl][nl] = xb[(size_t)(c0 + cl) * NPIX + n0 + nl];
        }
    }
    __syncthreads();
    {
        bf16* xtb = xt + (size_t)blockIdx.z * NPIX * CH;
        const int cp  = (tid & 15) * 4;
        const int nl0 = tid >> 4;
        #pragma unroll
        for (int i = 0; i < 4; ++i) {
            const int nl = nl0 + i * 16;
            ushort4 pk;
            #pragma unroll
            for (int j = 0; j < 4; ++j) {
                const bf16 h = __float2bfloat16(t[cp + j][nl]);
                ((unsigned short*)&pk)[j] = *(const unsigned short*)&h;
            }
            *(ushort4*)(xtb + (size_t)(n0 + nl) * CH + c0 + cp) = pk;
        }
    }
}

// ---------------------------------------------------------------------------
// Kernel 2 (v7): r8 schedule, n-tile 64.  As 32 KB (64 rows, full K=256) +
// Bs 2x8 KB = 48 KB LDS -> 3 blocks/CU (was 2).  Same staging, same
// stage->sync->compute loop, same A-locality (each A row staged 2x).
// 4 waves arranged 1x4 along o: wave owns 64n x 32o, acc[4][2] (32 VGPR),
// 8 MFMA/step.  Occupancy-at-constant-locality — the untested axis.
// grid (NPIX/64, CH/128, cnb)  block 256
// ---------------------------------------------------------------------------
__global__ __launch_bounds__(256, 2) void qkv_mfma(
    const bf16* __restrict__ xt, const bf16* __restrict__ Wb,
    const float* __restrict__ bq, const float* __restrict__ bk,
    const float* __restrict__ bv,
    bf16* __restrict__ qt, bf16* __restrict__ kt, bf16* __restrict__ vt)
{
    const int bl = blockIdx.z;
    const int n0 = blockIdx.x * 64;
    const int o0 = blockIdx.y * 128;
    const bf16* A = xt + (size_t)bl * NPIX * CH;

    __shared__ char As[64 * 512];      // 32 KB, full K=256
    __shared__ char Bs[2][128 * 64];   // 16 KB, double-buffered

    const int tid = threadIdx.x;
    const int wv  = tid >> 6, ln = tid & 63;
    const int wc  = wv;                 // wave owns o-range wc*32..wc*32+31
    const int lm  = ln & 15,  lk = ln >> 4;

    // stage all of A: 64 rows x 32 chunks = 2048 slots, 8 per thread
    #pragma unroll
    for (int t = 0; t < 8; ++t) {
        const int idx = t * 256 + tid;           // 0..2047 (16B units)
        const int row = idx >> 5, pos = idx & 31;
        const int chk = pos ^ (row & 7);
        glds16(A + (size_t)(n0 + row) * CH + chk * 8, &As[idx * 16]);
    }

    auto stageB = [&](int buf, const bf16* Wm, int k0) {
        #pragma unroll
        for (int it = 0; it < 2; ++it) {
            const int idx = it * 256 + tid;      // 0..511
            const int row = idx >> 2, pos = idx & 3;
            const int chk = pos ^ ((row >> 1) & 3);
            glds16(Wm + (size_t)(o0 + row) * CH + k0 + chk * 8, &Bs[buf][idx * 16]);
        }
    };

    stageB(0, Wb, 0);
    int buf = 0;

    bf16* const outs[3] = { qt + (size_t)bl * CH * NPIX,
                            kt + (size_t)bl * CH * NPIX,
                            vt + (size_t)bl * CH * NPIX };
    const float* const biases[3] = { bq, bk, bv };

    #pragma unroll
    for (int m = 0; m < 3; ++m) {
        f32x4 acc[4][2];
        #pragma unroll
        for (int i = 0; i < 4; ++i)
            #pragma unroll
            for (int j = 0; j < 2; ++j)
                #pragma unroll
                for (int r = 0; r < 4; ++r) acc[i][j][r] = 0.f;

        #pragma unroll
        for (int t = 0; t < 8; ++t) {
            __syncthreads();
            const int s = m * 8 + t;
            if (s < 23) {
                const int ns = s + 1;
                stageB(buf ^ 1, Wb + (size_t)(ns >> 3) * CH * CH, (ns & 7) * 32);
            }

            short8 afr[4], bfr[2];
            #pragma unroll
            for (int i = 0; i < 4; ++i) {
                const int row = i * 16 + lm;
                const int chunk = (t * 4 + lk) ^ (row & 7);
                afr[i] = *(const short8*)&As[row * 512 + chunk * 16];
            }
            #pragma unroll
            for (int j = 0; j < 2; ++j) {
                const int row = wc * 32 + j * 16 + lm;
                const int chk = lk ^ ((row >> 1) & 3);
                bfr[j] = *(const short8*)&Bs[buf][row * 64 + chk * 16];
            }
            #pragma unroll
            for (int i = 0; i < 4; ++i)
                #pragma unroll
                for (int j = 0; j < 2; ++j)
                    acc[i][j] = __builtin_amdgcn_mfma_f32_16x16x32_bf16(
                        afr[i], bfr[j], acc[i][j], 0, 0, 0);
            buf ^= 1;
        }

        // epilogue m: D row(reg) = n, col(lane&15) = o.  out layout [o][n].
        bf16* out = outs[m];
        const float* bias = biases[m];
        #pragma unroll
        for (int j = 0; j < 2; ++j) {
            const int o = o0 + wc * 32 + j * 16 + lm;
            const float bs = bias[o];
            #pragma unroll
            for (int i = 0; i < 4; ++i) {
                const int nb = n0 + i * 16 + lk * 4;
                ushort4 pk;
                #pragma unroll
                for (int r = 0; r < 4; ++r) {
                    const bf16 h = __float2bfloat16(acc[i][j][r] + bs);
                    ((unsigned short*)&pk)[r] = *(const unsigned short*)&h;
                }
                *(ushort4*)(out + (size_t)o * NPIX + nb) = pk;
            }
        }
    }
}

// ---------------------------------------------------------------------------
// Kernel 3: scores v5 — wave = 4 quads x 16 c-chunks (16 ch each).
// v6 (32 chunks x 2 quads) destroyed coalescing — keep 4-quad/64B groups.
// grid (100, cnb)  block 256
// ---------------------------------------------------------------------------
__global__ __launch_bounds__(256) void scores_kernel(
    const bf16* __restrict__ qt, const bf16* __restrict__ kt,
    float* __restrict__ scores, float* __restrict__ out0, int b0)
{
    const int tid   = threadIdx.x;
    const int wave  = tid >> 6;
    const int lane  = tid & 63;
    const int ql    = lane & 3;
    const int chunk = lane >> 2;

    const int qi = blockIdx.x * 16 + wave * 4 + ql;
    const int bl = blockIdx.y;
    const int b  = b0 + bl;
    const int n0 = qi * 4;
    const int r  = qi / 20;
    const int p0 = n0 - r * WW;

    const unsigned short* qp = (const unsigned short*)(qt + (size_t)bl * NPIX * CH)
                               + (size_t)chunk * 16 * NPIX;
    const unsigned short* kp = (const unsigned short*)(kt + (size_t)bl * NPIX * CH)
                               + (size_t)chunk * 16 * NPIX;

    const int rbm = max(r - 1, 0) * WW;
    const int rb0 = r * WW;
    const int rbp = min(r + 1, HH - 1) * WW;
    const bool eL = (p0 == 0), eR = (p0 == 76);

    float acc[4][9];
    #pragma unroll
    for (int px = 0; px < 4; ++px)
        #pragma unroll
        for (int j = 0; j < 9; ++j) acc[px][j] = 0.f;

    #pragma unroll 4
    for (int c = 0; c < 16; ++c) {
        const size_t cb = (size_t)c * NPIX;
        const ushort4 qv = *(const ushort4*)(qp + cb + n0);
        const float qf0 = b2f(qv.x), qf1 = b2f(qv.y), qf2 = b2f(qv.z), qf3 = b2f(qv.w);

        #pragma unroll
        for (int dr = 0; dr < 3; ++dr) {
            const int rb = (dr == 0) ? rbm : (dr == 1) ? rb0 : rbp;
            const short8 kw = *(const short8*)(kp + cb + rb + p0 - 2);
            const float w3 = b2f((unsigned short)kw[1]);
            const float w4 = b2f((unsigned short)kw[2]);
            const float w5 = b2f((unsigned short)kw[3]);
            const float w6 = b2f((unsigned short)kw[4]);
            const float w7 = b2f((unsigned short)kw[5]);
            const float w8 = b2f((unsigned short)kw[6]);

            acc[0][dr*3+0] += qf0 * w3;
            acc[0][dr*3+1] += qf0 * w4;
            acc[0][dr*3+2] += qf0 * w5;
            acc[1][dr*3+0] += qf1 * w4;
            acc[1][dr*3+1] += qf1 * w5;
            acc[1][dr*3+2] += qf1 * w6;
            acc[2][dr*3+0] += qf2 * w5;
            acc[2][dr*3+1] += qf2 * w6;
            acc[2][dr*3+2] += qf2 * w7;
            acc[3][dr*3+0] += qf3 * w6;
            acc[3][dr*3+1] += qf3 * w7;
            acc[3][dr*3+2] += qf3 * w8;
            if (eL) acc[0][dr*3+0] += qf0 * (w4 - w3);
            if (eR) acc[3][dr*3+2] += qf3 * (w7 - w8);
        }
    }

    #pragma unroll
    for (int px = 0; px < 4; ++px)
        #pragma unroll
        for (int j = 0; j < 9; ++j) {
            float v = acc[px][j];
            v += __shfl_xor(v, 4,  64);
            v += __shfl_xor(v, 8,  64);
            v += __shfl_xor(v, 16, 64);
            v += __shfl_xor(v, 32, 64);
            acc[px][j] = v;
        }

    float* sp = scores + (size_t)bl * 9 * NPIX;
    if (chunk < 9) {
        float4 v = { acc[0][chunk], acc[1][chunk], acc[2][chunk], acc[3][chunk] };
        *(float4*)(sp + (size_t)chunk * NPIX + n0) = v;
    } else if (chunk == 9) {
        float ssum[4];
        #pragma unroll
        for (int px = 0; px < 4; ++px) {
            float s = 0.f;
            #pragma unroll
            for (int j = 0; j < 9; ++j) s += acc[px][j];
            ssum[px] = s;
        }
        float* op = out0 + ((size_t)b * NPIX + n0) * 2;
        float4 o0v = { acc[0][4], (ssum[0] - acc[0][4]) * 0.125f,
                       acc[1][4], (ssum[1] - acc[1][4]) * 0.125f };
        float4 o1v = { acc[2][4], (ssum[2] - acc[2][4]) * 0.125f,
                       acc[3][4], (ssum[3] - acc[3][4]) * 0.125f };
        *(float4*)(op)     = o0v;
        *(float4*)(op + 4) = o1v;
    }
}

// ---------------------------------------------------------------------------
// Kernel 4 (v3): fused new_v + residual + LayerNorm, TWO channels per block.
// grid (CH/2, cnb)  block 320
// ---------------------------------------------------------------------------
__global__ __launch_bounds__(320) void newv_ln(
    const float* __restrict__ x, const bf16* __restrict__ vt,
    const float* __restrict__ scores, float* __restrict__ xout, int b0)
{
    __shared__ __align__(16) unsigned short lds_v[2][NPIX];
    __shared__ float rsum[5][2], rsq[5][2];

    const int cp2 = blockIdx.x;
    const int bl  = blockIdx.y;
    const int b   = b0 + bl;
    const int tid = threadIdx.x;

    const int4* vsrc = (const int4*)(vt + ((size_t)bl * CH + cp2 * 2) * NPIX);
    const float* xrow0 = x + ((size_t)b * CH + cp2 * 2) * NPIX;
    const float* xrow1 = xrow0 + NPIX;
    const float* sb    = scores + (size_t)bl * 9 * NPIX;

    float4 xv0[5], xv1[5];
    #pragma unroll
    for (int i = 0; i < 5; ++i) {
        const int n0 = (tid + i * 320) * 4;
        xv0[i] = *(const float4*)(xrow0 + n0);
        xv1[i] = *(const float4*)(xrow1 + n0);
    }

    #pragma unroll
    for (int i = 0; i < 5; ++i)
        ((int4*)lds_v)[tid + i * 320] = vsrc[tid + i * 320];
    __syncthreads();

    float val0[20], val1[20];
    float sum0 = 0.f, sq0 = 0.f, sum1 = 0.f, sq1 = 0.f;
    #pragma unroll
    for (int it = 0; it < 5; ++it) {
        const int p   = tid + it * 320;
        const int n0  = p * 4;
        const int r   = p / 20;
        const int c0  = (p % 20) * 4;

        const int rm = max(r - 1, 0) * WW;
        const int r0 = r * WW;
        const int rp = min(r + 1, HH - 1) * WW;

        float4 s[9];
        #pragma unroll
        for (int j = 0; j < 9; ++j)
            s[j] = *(const float4*)(sb + (size_t)j * NPIX + n0);

        const int cA = max(c0 - 1, 0);
        const int cF = min(c0 + 4, WW - 1);

        #pragma unroll
        for (int pl = 0; pl < 2; ++pl) {
            const unsigned short* lv = lds_v[pl];
            float vm[6], v0[6], vp[6];
            {
                const ushort4 a = *(const ushort4*)&lv[rm + c0];
                vm[1] = b2f(a.x); vm[2] = b2f(a.y); vm[3] = b2f(a.z); vm[4] = b2f(a.w);
                vm[0] = b2f(lv[rm + cA]); vm[5] = b2f(lv[rm + cF]);
            }
            {
                const ushort4 a = *(const ushort4*)&lv[r0 + c0];
                v0[1] = b2f(a.x); v0[2] = b2f(a.y); v0[3] = b2f(a.z); v0[4] = b2f(a.w);
                v0[0] = b2f(lv[r0 + cA]); v0[5] = b2f(lv[r0 + cF]);
            }
            {
                const ushort4 a = *(const ushort4*)&lv[rp + c0];
                vp[1] = b2f(a.x); vp[2] = b2f(a.y); vp[3] = b2f(a.z); vp[4] = b2f(a.w);
                vp[0] = b2f(lv[rp + cA]); vp[5] = b2f(lv[rp + cF]);
            }

            const float4 xin = pl ? xv1[it] : xv0[it];
            #pragma unroll
            for (int px = 0; px < 4; ++px) {
                float a;
                a  = ((const float*)&s[0])[px] * vm[px]
                   + ((const float*)&s[1])[px] * vm[px + 1]
                   + ((const float*)&s[2])[px] * vm[px + 2];
                a += ((const float*)&s[3])[px] * v0[px]
                   + ((const float*)&s[4])[px] * v0[px + 1]
                   + ((const float*)&s[5])[px] * v0[px + 2];
                a += ((const float*)&s[6])[px] * vp[px]
                   + ((const float*)&s[7])[px] * vp[px + 1]
                   + ((const float*)&s[8])[px] * vp[px + 2];
                const float vv = ((const float*)&xin)[px] + a;
                if (pl == 0) { val0[it * 4 + px] = vv; sum0 += vv; sq0 += vv * vv; }
                else         { val1[it * 4 + px] = vv; sum1 += vv; sq1 += vv * vv; }
            }
        }
    }

    #pragma unroll
    for (int off = 32; off >= 1; off >>= 1) {
        sum0 += __shfl_xor(sum0, off, 64);
        sq0  += __shfl_xor(sq0,  off, 64);
        sum1 += __shfl_xor(sum1, off, 64);
        sq1  += __shfl_xor(sq1,  off, 64);
    }
    const int wave = tid >> 6, lane = tid & 63;
    if (lane == 0) {
        rsum[wave][0] = sum0; rsq[wave][0] = sq0;
        rsum[wave][1] = sum1; rsq[wave][1] = sq1;
    }
    __syncthreads();
    sum0 = rsum[0][0] + rsum[1][0] + rsum[2][0] + rsum[3][0] + rsum[4][0];
    sq0  = rsq[0][0]  + rsq[1][0]  + rsq[2][0]  + rsq[3][0]  + rsq[4][0];
    sum1 = rsum[0][1] + rsum[1][1] + rsum[2][1] + rsum[3][1] + rsum[4][1];
    sq1  = rsq[0][1]  + rsq[1][1]  + rsq[2][1]  + rsq[3][1]  + rsq[4][1];

    const float mu0   = sum0 * (1.f / NPIX);
    const float var0  = sq0 * (1.f / NPIX) - mu0 * mu0;
    const float rstd0 = rsqrtf(var0 + 1e-5f);
    const float mu1   = sum1 * (1.f / NPIX);
    const float var1  = sq1 * (1.f / NPIX) - mu1 * mu1;
    const float rstd1 = rsqrtf(var1 + 1e-5f);

    float* orow0 = xout + ((size_t)b * CH + cp2 * 2) * NPIX;
    float* orow1 = orow0 + NPIX;
    #pragma unroll
    for (int it = 0; it < 5; ++it) {
        const int n0 = (tid + it * 320) * 4;
        float4 o0, o1;
        #pragma unroll
        for (int px = 0; px < 4; ++px) {
            ((float*)&o0)[px] = (val0[it * 4 + px] - mu0) * rstd0;
            ((float*)&o1)[px] = (val1[it * 4 + px] - mu1) * rstd1;
        }
        *(float4*)(orow0 + n0) = o0;
        *(float4*)(orow1 + n0) = o1;
    }
}

// ---------------------------------------------------------------------------
extern "C" void kernel_launch(void* const* d_in, const int* in_sizes, int n_in,
                              void* d_out, int out_size, void* d_ws, size_t ws_size,
                              hipStream_t stream)
{
    const float* x  = (const float*)d_in[0];
    const float* Wq = (const float*)d_in[1];
    const float* bq = (const float*)d_in[2];
    const float* Wk = (const float*)d_in[3];
    const float* bk = (const float*)d_in[4];
    const float* Wv = (const float*)d_in[5];
    const float* bv = (const float*)d_in[6];

    float* out0 = (float*)d_out;                       // [B][N][2]
    float* xout = out0 + (size_t)BATCH * NPIX * 2;     // [B][C][N]

    char* ws = (char*)d_ws;
    bf16* Wb = (bf16*)ws;
    ws += (size_t)3 * CH * CH * sizeof(bf16);          // 384 KiB

    const size_t fBF = (size_t)NPIX * CH * sizeof(bf16);   // 3.28 MB
    const size_t fSC = (size_t)NPIX * 9 * sizeof(float);   // 230 KB
    const size_t perBatch = 4 * fBF + fSC;                 // ~13.3 MB

    size_t avail = ws_size - ((size_t)3 * CH * CH * sizeof(bf16));
    int NB = (int)(avail / perBatch);
    if (NB < 1)  NB = 1;
    if (NB > BATCH) NB = BATCH;

    bf16*  xt  = (bf16*)ws;
    bf16*  qtb = (bf16*)(ws + (size_t)NB * fBF);
    bf16*  ktb = (bf16*)(ws + (size_t)NB * fBF * 2);
    bf16*  vtb = (bf16*)(ws + (size_t)NB * fBF * 3);
    float* sc  = (float*)(ws + (size_t)NB * fBF * 4);

    convert_w<<<dim3(CH * CH / 256, 3), 256, 0, stream>>>(Wq, Wk, Wv, Wb);

    for (int b0 = 0; b0 < BATCH; b0 += NB) {
        const int cnb = (BATCH - b0 < NB) ? (BATCH - b0) : NB;

        transpose_cast<<<dim3(NPIX / 64, CH / 64, cnb), 256, 0, stream>>>(x, xt, b0);

        qkv_mfma<<<dim3(NPIX / 64, CH / 128, cnb), 256, 0, stream>>>(
            xt, Wb, bq, bk, bv, qtb, ktb, vtb);

        scores_kernel<<<dim3(100, cnb), 256, 0, stream>>>(qtb, ktb, sc, out0, b0);

        newv_ln<<<dim3(CH / 2, cnb), 320, 0, stream>>>(x, vtb, sc, xout, b0);
    }
}